// Round 1
// baseline (508.372 us; speedup 1.0000x reference)
//
#include <hip/hip_runtime.h>
#include <stdint.h>

#define Hdim 1024
#define Bdim 8
#define Sdim 2048
#define Edim 8
#define Mtot 16384

typedef short bf16x8 __attribute__((ext_vector_type(8)));
typedef unsigned short u16x8 __attribute__((ext_vector_type(8)));
typedef float f32x4 __attribute__((ext_vector_type(4)));

__device__ __forceinline__ unsigned short f2bf(float f) {
  union { float f; unsigned u; } v; v.f = f;
  unsigned r = (v.u + 0x7FFFu + ((v.u >> 16) & 1u)) >> 16;
  return (unsigned short)r;
}

__device__ __forceinline__ void gload16(const void* g, void* l) {
  __builtin_amdgcn_global_load_lds((const __attribute__((address_space(1))) void*)g,
                                   (__attribute__((address_space(3))) void*)l,
                                   16, 0, 0);
}

// ---------------- kernel 1: f32 -> bf16 convert + per-(b,h) partial sums over s ----
// grid (S/32, B), block 256. part layout: [B][128][H]
__global__ void k_convert_mean(const float* __restrict__ x,
                               unsigned short* __restrict__ xb,
                               float* __restrict__ part) {
  const int b = blockIdx.y;
  const int s0 = blockIdx.x * 32;
  const int t = threadIdx.x;
  const int hg = (t & 127) << 3;   // 8 h per thread
  const int sp = t >> 7;           // s parity 0/1
  float accv[8];
#pragma unroll
  for (int q = 0; q < 8; ++q) accv[q] = 0.f;
#pragma unroll 4
  for (int i = 0; i < 16; ++i) {
    const int s = s0 + sp + (i << 1);
    const size_t base = ((size_t)b * Sdim + s) * Hdim + hg;
    const float4 lo = *(const float4*)(x + base);
    const float4 hi = *(const float4*)(x + base + 4);
    accv[0] += lo.x; accv[1] += lo.y; accv[2] += lo.z; accv[3] += lo.w;
    accv[4] += hi.x; accv[5] += hi.y; accv[6] += hi.z; accv[7] += hi.w;
    u16x8 pk;
    pk[0] = f2bf(lo.x); pk[1] = f2bf(lo.y); pk[2] = f2bf(lo.z); pk[3] = f2bf(lo.w);
    pk[4] = f2bf(hi.x); pk[5] = f2bf(hi.y); pk[6] = f2bf(hi.z); pk[7] = f2bf(hi.w);
    *(u16x8*)(xb + base) = pk;
  }
  float* pp = part + ((size_t)b * 128 + blockIdx.x * 2 + sp) * Hdim + hg;
#pragma unroll
  for (int q = 0; q < 8; ++q) pp[q] = accv[q];
}

// ---------------- kernel 2: We [E][H][H] f32 -> Wt [E][d][h] bf16 (transposed) -----
// grid (H/64, H/64, E), block 256
__global__ void k_transpose_w(const float* __restrict__ We,
                              unsigned short* __restrict__ wt) {
  __shared__ float lds[64][65];
  const int e = blockIdx.z, hb = blockIdx.y, db = blockIdx.x;
  const int t = threadIdx.x;
  const float* src = We + ((size_t)e * Hdim + hb * 64) * Hdim + db * 64;
#pragma unroll 4
  for (int it = 0; it < 16; ++it) {
    int idx = it * 256 + t;
    int r = idx >> 6, c = idx & 63;
    lds[r][c] = src[(size_t)r * Hdim + c];
  }
  __syncthreads();
  unsigned short* dst = wt + ((size_t)e * Hdim + db * 64) * Hdim + hb * 64;
#pragma unroll 4
  for (int it = 0; it < 16; ++it) {
    int idx = it * 256 + t;
    int r = idx >> 6, c = idx & 63;
    dst[(size_t)r * Hdim + c] = f2bf(lds[c][r]);
  }
}

// ---------------- kernel 3: finish mean + h = relu(xm @ Wr1 + br1) -----------------
// grid (H/256, B), block 256
__global__ void k_router1(const float* __restrict__ part,
                          const float* __restrict__ Wr1,
                          const float* __restrict__ br1,
                          float* __restrict__ hbuf) {
  __shared__ float xm[Hdim];
  const int b = blockIdx.y, jc = blockIdx.x, t = threadIdx.x;
  for (int k = t; k < Hdim; k += 256) {
    float s = 0.f;
    const float* p = part + (size_t)b * 128 * Hdim + k;
#pragma unroll 8
    for (int c = 0; c < 128; ++c) s += p[(size_t)c * Hdim];
    xm[k] = s * (1.0f / 2048.0f);
  }
  __syncthreads();
  const int j = jc * 256 + t;
  float acc = br1[j];
#pragma unroll 8
  for (int k = 0; k < Hdim; ++k) acc = fmaf(xm[k], Wr1[(size_t)k * Hdim + j], acc);
  hbuf[b * Hdim + j] = fmaxf(acc, 0.f);
}

// ---------------- kernel 4: logits + softmax -> routing [B][E] ---------------------
// 1 block, 64 threads (lane = b*8+e)
__global__ void k_router2(const float* __restrict__ hbuf,
                          const float* __restrict__ Wr2,
                          const float* __restrict__ br2,
                          float* __restrict__ routing) {
  const int t = threadIdx.x;
  const int b = t >> 3, e = t & 7;
  float acc = br2[e];
  const float* hb = hbuf + b * Hdim;
#pragma unroll 8
  for (int k = 0; k < Hdim; ++k) acc = fmaf(hb[k], Wr2[k * Edim + e], acc);
  float m = acc;
  for (int d = 1; d < 8; d <<= 1) m = fmaxf(m, __shfl_xor(m, d, 64));
  float p = __expf(acc - m);
  float s = p;
  for (int d = 1; d < 8; d <<= 1) s += __shfl_xor(s, d, 64);
  routing[t] = p / s;
}

// ---------------- kernel 5: fused all-expert GEMM + relu + routing-weighted sum ----
// grid (H/BN, Mtot/BM), block 256 (4 waves, 2x2, each 64x64)
#define BM 128
#define BN 128
#define BK 64

__global__ __launch_bounds__(256, 2)
void k_moe_gemm(const unsigned short* __restrict__ xb,
                const unsigned short* __restrict__ wt,
                const float* __restrict__ be,
                const float* __restrict__ routing,
                float* __restrict__ out) {
  __shared__ unsigned short As[BM * BK];  // [128][64] row-major
  __shared__ unsigned short Bs[BN * BK];  // [128][64] row-major (rows = d)
  const int t = threadIdx.x;
  const int wave = t >> 6, lane = t & 63;
  const int wr = wave >> 1, wc = wave & 1;
  const int m0 = blockIdx.y * BM;
  const int n0 = blockIdx.x * BN;
  const int bidx = m0 >> 11;  // token-block / 2048 -> batch index (tiles never straddle b)

  // staging: 16 chunks of 1KB per tile; chunk c covers rows [c*8, c*8+8)
  const int srow = lane >> 3;
  const int scol = (lane & 7) << 3;

  // fragment addressing (16x16x32: A row = lane&15, k0 = (lane>>4)*8)
  const int arow = wr * 64 + (lane & 15);
  const int brow = wc * 64 + (lane & 15);
  const int kfr  = (lane >> 4) << 3;

  f32x4 oacc[4][4];
#pragma unroll
  for (int i = 0; i < 4; ++i)
#pragma unroll
    for (int j = 0; j < 4; ++j) oacc[i][j] = (f32x4){0.f, 0.f, 0.f, 0.f};

  for (int e = 0; e < Edim; ++e) {
    const unsigned short* wte = wt + (size_t)e * Hdim * Hdim;
    f32x4 acc[4][4];
#pragma unroll
    for (int i = 0; i < 4; ++i)
#pragma unroll
      for (int j = 0; j < 4; ++j) acc[i][j] = (f32x4){0.f, 0.f, 0.f, 0.f};

    for (int k0 = 0; k0 < Hdim; k0 += BK) {
      __syncthreads();  // previous tile fully consumed
#pragma unroll
      for (int p = 0; p < 4; ++p) {
        const int chunk = p * 4 + wave;
        const int row = chunk * 8 + srow;
        gload16(xb + (size_t)(m0 + row) * Hdim + k0 + scol, &As[chunk * 512]);
      }
#pragma unroll
      for (int p = 0; p < 4; ++p) {
        const int chunk = p * 4 + wave;
        const int row = chunk * 8 + srow;
        gload16(wte + (size_t)(n0 + row) * Hdim + k0 + scol, &Bs[chunk * 512]);
      }
      __syncthreads();  // compiler drains vmcnt before barrier -> LDS ready
#pragma unroll
      for (int kk = 0; kk < 2; ++kk) {
        bf16x8 af[4], bf[4];
#pragma unroll
        for (int i = 0; i < 4; ++i)
          af[i] = *(const bf16x8*)&As[(arow + i * 16) * BK + kk * 32 + kfr];
#pragma unroll
        for (int j = 0; j < 4; ++j)
          bf[j] = *(const bf16x8*)&Bs[(brow + j * 16) * BK + kk * 32 + kfr];
#pragma unroll
        for (int i = 0; i < 4; ++i)
#pragma unroll
          for (int j = 0; j < 4; ++j)
            acc[i][j] = __builtin_amdgcn_mfma_f32_16x16x32_bf16(af[i], bf[j], acc[i][j], 0, 0, 0);
      }
    }

    // epilogue: out_acc += routing[b,e] * relu(acc + be[e,d])
    const float rw = routing[bidx * Edim + e];
#pragma unroll
    for (int j = 0; j < 4; ++j) {
      const float bias = be[e * Hdim + n0 + wc * 64 + j * 16 + (lane & 15)];
#pragma unroll
      for (int i = 0; i < 4; ++i)
#pragma unroll
        for (int r = 0; r < 4; ++r) {
          float v = acc[i][j][r] + bias;
          oacc[i][j][r] = fmaf(fmaxf(v, 0.f), rw, oacc[i][j][r]);
        }
    }
  }

  // write out: D row = (lane>>4)*4 + r, col = lane&15
#pragma unroll
  for (int i = 0; i < 4; ++i) {
    const int row0 = m0 + wr * 64 + i * 16 + ((lane >> 4) << 2);
#pragma unroll
    for (int j = 0; j < 4; ++j) {
      const int col = n0 + wc * 64 + j * 16 + (lane & 15);
#pragma unroll
      for (int r = 0; r < 4; ++r)
        out[(size_t)(row0 + r) * Hdim + col] = oacc[i][j][r];
    }
  }
}

extern "C" void kernel_launch(void* const* d_in, const int* in_sizes, int n_in,
                              void* d_out, int out_size, void* d_ws, size_t ws_size,
                              hipStream_t stream) {
  const float* x   = (const float*)d_in[0];
  const float* We  = (const float*)d_in[1];
  const float* be  = (const float*)d_in[2];
  const float* Wr1 = (const float*)d_in[3];
  const float* br1 = (const float*)d_in[4];
  const float* Wr2 = (const float*)d_in[5];
  const float* br2 = (const float*)d_in[6];
  float* out = (float*)d_out;

  char* ws = (char*)d_ws;
  unsigned short* xb = (unsigned short*)ws;                    // 33,554,432 B
  unsigned short* wt = (unsigned short*)(ws + 33554432);       // 16,777,216 B
  float* part    = (float*)(ws + 50331648);                    //  4,194,304 B
  float* hbuf    = (float*)(ws + 54525952);                    //     32,768 B
  float* routing = (float*)(ws + 54558720);                    //        256 B

  k_convert_mean<<<dim3(Sdim / 32, Bdim), 256, 0, stream>>>(x, xb, part);
  k_transpose_w<<<dim3(Hdim / 64, Hdim / 64, Edim), 256, 0, stream>>>(We, wt);
  k_router1<<<dim3(Hdim / 256, Bdim), 256, 0, stream>>>(part, Wr1, br1, hbuf);
  k_router2<<<1, 64, 0, stream>>>(hbuf, Wr2, br2, routing);
  k_moe_gemm<<<dim3(Hdim / BN, Mtot / BM), 256, 0, stream>>>(xb, wt, be, routing, out);
}

// Round 2
// 481.923 us; speedup vs baseline: 1.0549x; 1.0549x over previous
//
#include <hip/hip_runtime.h>
#include <stdint.h>

#define Hdim 1024
#define Bdim 8
#define Sdim 2048
#define Edim 8
#define Mtot 16384
#define Ntot 8192   // n' = d*8 + e

typedef short bf16x8 __attribute__((ext_vector_type(8)));
typedef unsigned short u16x8 __attribute__((ext_vector_type(8)));
typedef float f32x4 __attribute__((ext_vector_type(4)));

__device__ __forceinline__ unsigned short f2bf(float f) {
  union { float f; unsigned u; } v; v.f = f;
  unsigned r = (v.u + 0x7FFFu + ((v.u >> 16) & 1u)) >> 16;
  return (unsigned short)r;
}

__device__ __forceinline__ void gload16(const void* g, void* l) {
  __builtin_amdgcn_global_load_lds((const __attribute__((address_space(1))) void*)g,
                                   (__attribute__((address_space(3))) void*)l,
                                   16, 0, 0);
}

#define VMCNT_(N) asm volatile("s_waitcnt vmcnt(" #N ")" ::: "memory")
#define VMCNT(N) VMCNT_(N)

// ---------------- kernel 1: f32 -> bf16 convert + per-(b,h) partial sums over s ----
__global__ void k_convert_mean(const float* __restrict__ x,
                               unsigned short* __restrict__ xb,
                               float* __restrict__ part) {
  const int b = blockIdx.y;
  const int s0 = blockIdx.x * 32;
  const int t = threadIdx.x;
  const int hg = (t & 127) << 3;
  const int sp = t >> 7;
  float accv[8];
#pragma unroll
  for (int q = 0; q < 8; ++q) accv[q] = 0.f;
#pragma unroll 4
  for (int i = 0; i < 16; ++i) {
    const int s = s0 + sp + (i << 1);
    const size_t base = ((size_t)b * Sdim + s) * Hdim + hg;
    const float4 lo = *(const float4*)(x + base);
    const float4 hi = *(const float4*)(x + base + 4);
    accv[0] += lo.x; accv[1] += lo.y; accv[2] += lo.z; accv[3] += lo.w;
    accv[4] += hi.x; accv[5] += hi.y; accv[6] += hi.z; accv[7] += hi.w;
    u16x8 pk;
    pk[0] = f2bf(lo.x); pk[1] = f2bf(lo.y); pk[2] = f2bf(lo.z); pk[3] = f2bf(lo.w);
    pk[4] = f2bf(hi.x); pk[5] = f2bf(hi.y); pk[6] = f2bf(hi.z); pk[7] = f2bf(hi.w);
    *(u16x8*)(xb + base) = pk;
  }
  float* pp = part + ((size_t)b * 128 + blockIdx.x * 2 + sp) * Hdim + hg;
#pragma unroll
  for (int q = 0; q < 8; ++q) pp[q] = accv[q];
}

// ---------------- kernel 2: We [E][H][H] f32 -> wt [(d*8+e)][h] bf16 ----------------
__global__ void k_transpose_w(const float* __restrict__ We,
                              unsigned short* __restrict__ wt) {
  __shared__ float lds[64][65];
  const int e = blockIdx.z, hb = blockIdx.y, db = blockIdx.x;
  const int t = threadIdx.x;
  const float* src = We + ((size_t)e * Hdim + hb * 64) * Hdim + db * 64;
#pragma unroll 4
  for (int it = 0; it < 16; ++it) {
    int idx = it * 256 + t;
    int r = idx >> 6, c = idx & 63;
    lds[r][c] = src[(size_t)r * Hdim + c];
  }
  __syncthreads();
#pragma unroll 4
  for (int it = 0; it < 16; ++it) {
    int idx = it * 256 + t;
    int r = idx >> 6, c = idx & 63;   // r = d_local, c = h_local
    const int np = (db * 64 + r) * 8 + e;
    wt[(size_t)np * Hdim + hb * 64 + c] = f2bf(lds[c][r]);
  }
}

// ---------------- kernel 3: finish mean + h = relu(xm @ Wr1 + br1) -----------------
__global__ void k_router1(const float* __restrict__ part,
                          const float* __restrict__ Wr1,
                          const float* __restrict__ br1,
                          float* __restrict__ hbuf) {
  __shared__ float xm[Hdim];
  const int b = blockIdx.y, jc = blockIdx.x, t = threadIdx.x;
  for (int k = t; k < Hdim; k += 256) {
    float s = 0.f;
    const float* p = part + (size_t)b * 128 * Hdim + k;
#pragma unroll 8
    for (int c = 0; c < 128; ++c) s += p[(size_t)c * Hdim];
    xm[k] = s * (1.0f / 2048.0f);
  }
  __syncthreads();
  const int j = jc * 256 + t;
  float acc = br1[j];
#pragma unroll 8
  for (int k = 0; k < Hdim; ++k) acc = fmaf(xm[k], Wr1[(size_t)k * Hdim + j], acc);
  hbuf[b * Hdim + j] = fmaxf(acc, 0.f);
}

// ---------------- kernel 4: logits + softmax -> routing [B][E] ---------------------
__global__ void k_router2(const float* __restrict__ hbuf,
                          const float* __restrict__ Wr2,
                          const float* __restrict__ br2,
                          float* __restrict__ routing) {
  const int t = threadIdx.x;
  const int e = t & 7;
  const int b = t >> 3;
  float acc = br2[e];
  const float* hb = hbuf + b * Hdim;
#pragma unroll 8
  for (int k = 0; k < Hdim; ++k) acc = fmaf(hb[k], Wr2[k * Edim + e], acc);
  float m = acc;
  for (int d = 1; d < 8; d <<= 1) m = fmaxf(m, __shfl_xor(m, d, 64));
  float p = __expf(acc - m);
  float s = p;
  for (int d = 1; d < 8; d <<= 1) s += __shfl_xor(s, d, 64);
  routing[t] = p / s;
}

// ---------------- kernel 5: single fused GEMM 16384 x 8192 x 1024 ------------------
// 256x256 tile, BK=32, 8 waves (2x4), 4-deep circular LDS dbuf, swizzled layout.
// LDS: bufA[k] @ k*16384 (k=0..3), bufB[k] @ 65536 + k*16384. Total 128 KiB dynamic.
__global__ __launch_bounds__(512, 2)
void k_moe_gemm(const unsigned short* __restrict__ xb,
                const unsigned short* __restrict__ wt,
                const float* __restrict__ be,
                const float* __restrict__ routing,
                float* __restrict__ out) {
  extern __shared__ char smem[];
  const int t = threadIdx.x;
  const int wave = t >> 6, lane = t & 63;
  const int la15 = lane & 15;
  const int wr = wave >> 2;    // 0..1  (row half)
  const int wcn = wave & 3;    // 0..3  (col quarter)

  // bijective XCD swizzle (2048 % 8 == 0)
  const int bid = blockIdx.x;
  const int wg = (bid & 7) * 256 + (bid >> 3);
  const int m0 = (wg >> 5) * 256;
  const int n0 = (wg & 31) * 256;

  // --- staging constants: thread t loads row (q*128 + t>>2), swizzled chunk (t&3) ---
  const int rr0 = t >> 2;                                   // 0..127
  const int cs = (((t & 3) ^ ((rr0 >> 1) & 3)) << 3);       // element offset in row
  const unsigned short* aSrc0 = xb + (size_t)(m0 + rr0) * Hdim + cs;
  const unsigned short* bSrc0 = wt + (size_t)(n0 + rr0) * Hdim + cs;
  char* ldsA = smem;
  char* ldsB = smem + 65536;
  const int woff = wave * 1024;

  // --- ds_read bases: row-major 64B rows, chunk ^= (row>>1)&3 ---
  const int swz = (((lane >> 4) ^ ((la15 >> 1) & 3)) << 4);
  const int aRdOff = (wr * 128 + la15) * 64 + swz;          // + (p&3)*16384 + i*1024
  const int bRdOff = (wcn * 64 + la15) * 64 + swz;          // + 65536 + (p&3)*16384 + j*1024

  f32x4 acc[8][4];
#pragma unroll
  for (int i = 0; i < 8; ++i)
#pragma unroll
    for (int j = 0; j < 4; ++j) acc[i][j] = (f32x4){0.f, 0.f, 0.f, 0.f};

#define STAGE(pt) { \
    const int buf_ = (pt) & 3; const int k0_ = (pt) * 32; \
    gload16(aSrc0 + k0_,               ldsA + buf_ * 16384 + woff); \
    gload16(aSrc0 + 128 * Hdim + k0_,  ldsA + buf_ * 16384 + 8192 + woff); \
    gload16(bSrc0 + k0_,               ldsB + buf_ * 16384 + woff); \
    gload16(bSrc0 + 128 * Hdim + k0_,  ldsB + buf_ * 16384 + 8192 + woff); \
  }

#define PHASE_BODY(p, DO_STAGE) { \
    const char* ra_ = smem + ((p) & 3) * 16384 + aRdOff; \
    const char* rb_ = smem + 65536 + ((p) & 3) * 16384 + bRdOff; \
    bf16x8 af[8]; bf16x8 bf[4]; \
    _Pragma("unroll") for (int i_ = 0; i_ < 8; ++i_) af[i_] = *(const bf16x8*)(ra_ + i_ * 1024); \
    _Pragma("unroll") for (int j_ = 0; j_ < 4; ++j_) bf[j_] = *(const bf16x8*)(rb_ + j_ * 1024); \
    if (DO_STAGE) STAGE((p) + 3); \
    __builtin_amdgcn_s_barrier(); \
    asm volatile("s_waitcnt lgkmcnt(0)" ::: "memory"); \
    __builtin_amdgcn_s_setprio(1); \
    _Pragma("unroll") for (int i_ = 0; i_ < 8; ++i_) \
      _Pragma("unroll") for (int j_ = 0; j_ < 4; ++j_) \
        acc[i_][j_] = __builtin_amdgcn_mfma_f32_16x16x32_bf16(af[i_], bf[j_], acc[i_][j_], 0, 0, 0); \
    __builtin_amdgcn_s_setprio(0); \
  }

  // prologue: stage tiles 0,1,2; wait tile 0 (8 = two tiles in flight)
  STAGE(0); STAGE(1); STAGE(2);
  VMCNT(8);
  __builtin_amdgcn_s_barrier();

#pragma unroll 4
  for (int p = 0; p < 28; ++p) {
    PHASE_BODY(p, 1);
    VMCNT(8);
    __builtin_amdgcn_s_barrier();
  }
  PHASE_BODY(28, 1);   // stages tile 31
  VMCNT(8);
  __builtin_amdgcn_s_barrier();
  PHASE_BODY(29, 0);
  VMCNT(4);
  __builtin_amdgcn_s_barrier();
  PHASE_BODY(30, 0);
  VMCNT(0);
  __builtin_amdgcn_s_barrier();
  PHASE_BODY(31, 0);
  __builtin_amdgcn_s_barrier();   // all LDS reads done -> safe to reuse as out staging

  // ---------------- epilogue: bias + relu + routing weight + e-reduce ----------------
  float* outb = (float*)smem;                 // [256][33] padded
  const int bidx = m0 >> 11;                  // batch (2048 rows per b, tile never straddles)
  const float rw = routing[bidx * Edim + (lane & 7)];
  const int dblk = (lane >> 3) & 1;
  const bool writer = ((lane & 7) == 0);
#pragma unroll
  for (int j = 0; j < 4; ++j) {
    const int col0 = wcn * 64 + j * 16;       // within-tile n' base of fragment
    const float bias = be[(lane & 7) * Hdim + (n0 >> 3) + (col0 >> 3) + dblk];
#pragma unroll
    for (int i = 0; i < 8; ++i) {
#pragma unroll
      for (int r = 0; r < 4; ++r) {
        float v = fmaxf(acc[i][j][r] + bias, 0.f) * rw;
        v += __shfl_xor(v, 1, 64);
        v += __shfl_xor(v, 2, 64);
        v += __shfl_xor(v, 4, 64);
        if (writer) {
          const int row = wr * 128 + i * 16 + ((lane >> 4) << 2) + r;
          outb[row * 33 + (col0 >> 3) + dblk] = v;
        }
      }
    }
  }
  __builtin_amdgcn_s_barrier();
  // coalesced store of the block's 256 x 32 f32 out-tile
  const size_t obase = (size_t)m0 * Hdim + (n0 >> 3);
#pragma unroll
  for (int it = 0; it < 4; ++it) {
    const int r = it * 64 + (t >> 3);
    const int c = (t & 7) * 4;
    float4 vv;
    vv.x = outb[r * 33 + c];
    vv.y = outb[r * 33 + c + 1];
    vv.z = outb[r * 33 + c + 2];
    vv.w = outb[r * 33 + c + 3];
    *(float4*)(out + obase + (size_t)r * Hdim + c) = vv;
  }
#undef STAGE
#undef PHASE_BODY
}

extern "C" void kernel_launch(void* const* d_in, const int* in_sizes, int n_in,
                              void* d_out, int out_size, void* d_ws, size_t ws_size,
                              hipStream_t stream) {
  const float* x   = (const float*)d_in[0];
  const float* We  = (const float*)d_in[1];
  const float* be  = (const float*)d_in[2];
  const float* Wr1 = (const float*)d_in[3];
  const float* br1 = (const float*)d_in[4];
  const float* Wr2 = (const float*)d_in[5];
  const float* br2 = (const float*)d_in[6];
  float* out = (float*)d_out;

  char* ws = (char*)d_ws;
  unsigned short* xb = (unsigned short*)ws;                  // 33,554,432 B
  unsigned short* wt = (unsigned short*)(ws + 33554432);     // 16,777,216 B
  float* part    = (float*)(ws + 50331648);                  //  4,194,304 B
  float* hbuf    = (float*)(ws + 54525952);                  //     32,768 B
  float* routing = (float*)(ws + 54558720);                  //        256 B

  hipFuncSetAttribute((const void*)k_moe_gemm,
                      hipFuncAttributeMaxDynamicSharedMemorySize, 131072);

  k_convert_mean<<<dim3(Sdim / 32, Bdim), 256, 0, stream>>>(x, xb, part);
  k_transpose_w<<<dim3(Hdim / 64, Hdim / 64, Edim), 256, 0, stream>>>(We, wt);
  k_router1<<<dim3(Hdim / 256, Bdim), 256, 0, stream>>>(part, Wr1, br1, hbuf);
  k_router2<<<1, 64, 0, stream>>>(hbuf, Wr2, br2, routing);
  k_moe_gemm<<<dim3(2048), 512, 131072, stream>>>(xb, wt, be, routing, out);
}

// Round 3
// 462.172 us; speedup vs baseline: 1.1000x; 1.0427x over previous
//
#include <hip/hip_runtime.h>
#include <stdint.h>

#define Hdim 1024
#define Bdim 8
#define Sdim 2048
#define Edim 8
#define Mtot 16384
#define Ntot 8192   // n' = d*8 + e

typedef short bf16x8 __attribute__((ext_vector_type(8)));
typedef unsigned short u16x8 __attribute__((ext_vector_type(8)));
typedef float f32x4 __attribute__((ext_vector_type(4)));

__device__ __forceinline__ unsigned short f2bf(float f) {
  union { float f; unsigned u; } v; v.f = f;
  unsigned r = (v.u + 0x7FFFu + ((v.u >> 16) & 1u)) >> 16;
  return (unsigned short)r;
}

__device__ __forceinline__ void gload16(const void* g, void* l) {
  __builtin_amdgcn_global_load_lds((const __attribute__((address_space(1))) void*)g,
                                   (__attribute__((address_space(3))) void*)l,
                                   16, 0, 0);
}

#define VMCNT_(N) asm volatile("s_waitcnt vmcnt(" #N ")" ::: "memory")
#define VMCNT(N) VMCNT_(N)
#define BAR() __builtin_amdgcn_s_barrier()

// ---------------- kernel 1: f32 -> bf16 convert + per-(b,h) partial sums over s ----
__global__ void k_convert_mean(const float* __restrict__ x,
                               unsigned short* __restrict__ xb,
                               float* __restrict__ part) {
  const int b = blockIdx.y;
  const int s0 = blockIdx.x * 32;
  const int t = threadIdx.x;
  const int hg = (t & 127) << 3;
  const int sp = t >> 7;
  float accv[8];
#pragma unroll
  for (int q = 0; q < 8; ++q) accv[q] = 0.f;
#pragma unroll 4
  for (int i = 0; i < 16; ++i) {
    const int s = s0 + sp + (i << 1);
    const size_t base = ((size_t)b * Sdim + s) * Hdim + hg;
    const float4 lo = *(const float4*)(x + base);
    const float4 hi = *(const float4*)(x + base + 4);
    accv[0] += lo.x; accv[1] += lo.y; accv[2] += lo.z; accv[3] += lo.w;
    accv[4] += hi.x; accv[5] += hi.y; accv[6] += hi.z; accv[7] += hi.w;
    u16x8 pk;
    pk[0] = f2bf(lo.x); pk[1] = f2bf(lo.y); pk[2] = f2bf(lo.z); pk[3] = f2bf(lo.w);
    pk[4] = f2bf(hi.x); pk[5] = f2bf(hi.y); pk[6] = f2bf(hi.z); pk[7] = f2bf(hi.w);
    *(u16x8*)(xb + base) = pk;
  }
  float* pp = part + ((size_t)b * 128 + blockIdx.x * 2 + sp) * Hdim + hg;
#pragma unroll
  for (int q = 0; q < 8; ++q) pp[q] = accv[q];
}

// ---------------- kernel 2: We [E][H][H] f32 -> wt [(d*8+e)][h] bf16 ----------------
__global__ void k_transpose_w(const float* __restrict__ We,
                              unsigned short* __restrict__ wt) {
  __shared__ float lds[64][65];
  const int e = blockIdx.z, hb = blockIdx.y, db = blockIdx.x;
  const int t = threadIdx.x;
  const float* src = We + ((size_t)e * Hdim + hb * 64) * Hdim + db * 64;
#pragma unroll 4
  for (int it = 0; it < 16; ++it) {
    int idx = it * 256 + t;
    int r = idx >> 6, c = idx & 63;
    lds[r][c] = src[(size_t)r * Hdim + c];
  }
  __syncthreads();
#pragma unroll 4
  for (int it = 0; it < 16; ++it) {
    int idx = it * 256 + t;
    int r = idx >> 6, c = idx & 63;   // r = d_local, c = h_local
    const int np = (db * 64 + r) * 8 + e;
    wt[(size_t)np * Hdim + hb * 64 + c] = f2bf(lds[c][r]);
  }
}

// ---------------- kernel 3: finish mean + h = relu(xm @ Wr1 + br1) -----------------
__global__ void k_router1(const float* __restrict__ part,
                          const float* __restrict__ Wr1,
                          const float* __restrict__ br1,
                          float* __restrict__ hbuf) {
  __shared__ float xm[Hdim];
  const int b = blockIdx.y, jc = blockIdx.x, t = threadIdx.x;
  for (int k = t; k < Hdim; k += 256) {
    float s = 0.f;
    const float* p = part + (size_t)b * 128 * Hdim + k;
#pragma unroll 8
    for (int c = 0; c < 128; ++c) s += p[(size_t)c * Hdim];
    xm[k] = s * (1.0f / 2048.0f);
  }
  __syncthreads();
  const int j = jc * 256 + t;
  float acc = br1[j];
#pragma unroll 8
  for (int k = 0; k < Hdim; ++k) acc = fmaf(xm[k], Wr1[(size_t)k * Hdim + j], acc);
  hbuf[b * Hdim + j] = fmaxf(acc, 0.f);
}

// ---------------- kernel 4: logits + softmax -> routing [B][E] ---------------------
__global__ void k_router2(const float* __restrict__ hbuf,
                          const float* __restrict__ Wr2,
                          const float* __restrict__ br2,
                          float* __restrict__ routing) {
  const int t = threadIdx.x;
  const int e = t & 7;
  const int b = t >> 3;
  float acc = br2[e];
  const float* hb = hbuf + b * Hdim;
#pragma unroll 8
  for (int k = 0; k < Hdim; ++k) acc = fmaf(hb[k], Wr2[k * Edim + e], acc);
  float m = acc;
  for (int d = 1; d < 8; d <<= 1) m = fmaxf(m, __shfl_xor(m, d, 64));
  float p = __expf(acc - m);
  float s = p;
  for (int d = 1; d < 8; d <<= 1) s += __shfl_xor(s, d, 64);
  routing[t] = p / s;
}

// ---------------- kernel 5: 8-phase 256x256 fused GEMM 16384 x 8192 x 1024 ---------
// 8 waves (2M x 4N), per-wave 128x64 C. BK=64 per tile, 2 tiles per iteration.
// LDS: A buf0/1 @ 0/32768, B buf0/1 @ 65536/98304. XOR-swizzled 16B chunks.
__global__ __launch_bounds__(512, 2)
void k_moe_gemm(const unsigned short* __restrict__ xb,
                const unsigned short* __restrict__ wt,
                const float* __restrict__ be,
                const float* __restrict__ routing,
                float* __restrict__ out) {
  extern __shared__ char smem[];
  const int t = threadIdx.x;
  const int wave = t >> 6, lane = t & 63;
  const int la15 = lane & 15;
  const int wr = wave >> 2;    // 0..1
  const int wcn = wave & 3;    // 0..3

  // bijective XCD swizzle (2048 % 8 == 0)
  const int bid = blockIdx.x;
  const int wg = (bid & 7) * 256 + (bid >> 3);
  const int m0 = (wg >> 5) * 256;
  const int n0 = (wg & 31) * 256;

  // --- staging bases: thread covers row base + (lane>>3), phys chunk lane&7,
  //     global logical chunk = (lane&7) ^ (lane>>3)  (row&7 == lane>>3 always)
  const int cx = (((lane & 7) ^ (lane >> 3)) << 3);
  const unsigned short* aStage = xb + (size_t)(m0 + wave * 8 + (lane >> 3)) * Hdim + cx;
  const int bRowLoc = ((wave & 3) << 3) + ((wave >> 2) << 6) + (lane >> 3);
  const unsigned short* bStage = wt + (size_t)(n0 + bRowLoc) * Hdim + cx;
  const int aLdsW = wave * 1024;
  const int bLdsW = ((wave & 3) << 10) + ((wave >> 2) << 13);

  // --- ds_read bases (physical chunk = logical ^ (row&7), row&7 == lane&7) ---
  const int swz0 = (((lane >> 4) ^ (lane & 7)) << 4);
  const int swz1 = ((((lane >> 4) + 4) ^ (lane & 7)) << 4);
  const int aRd = (wr * 128 + la15) * 128;
  const int bRd = (wcn * 64 + la15) * 128;

  f32x4 acc[8][4];
#pragma unroll
  for (int i = 0; i < 8; ++i)
#pragma unroll
    for (int j = 0; j < 4; ++j) acc[i][j] = (f32x4){0.f, 0.f, 0.f, 0.f};

  // unit = 16KB, 2 gloads. A half: rows {h*64..h*64+63, 128+h*64..}.
  // B sub: rows with bit5==sub across all wcn quarters.
#define STG_A(half, buf, k0) do { \
    gload16(aStage + (half) * 64 * 1024 + (k0),          smem + (buf) * 32768 + aLdsW + (half) * 8192); \
    gload16(aStage + (128 + (half) * 64) * 1024 + (k0),  smem + (buf) * 32768 + aLdsW + 16384 + (half) * 8192); \
  } while (0)
#define STG_B(sub, buf, k0) do { \
    gload16(bStage + (sub) * 32 * 1024 + (k0),           smem + 65536 + (buf) * 32768 + bLdsW + (sub) * 4096); \
    gload16(bStage + (128 + (sub) * 32) * 1024 + (k0),   smem + 65536 + (buf) * 32768 + bLdsW + 16384 + (sub) * 4096); \
  } while (0)
#define LD_A(dst, buf, qi) do { \
    _Pragma("unroll") for (int ii = 0; ii < 4; ++ii) { \
      dst[ii][0] = *(const bf16x8*)(smem + (buf) * 32768 + aRd + (qi) * 8192 + ii * 2048 + swz0); \
      dst[ii][1] = *(const bf16x8*)(smem + (buf) * 32768 + aRd + (qi) * 8192 + ii * 2048 + swz1); } \
  } while (0)
#define LD_B(dst, buf, qj) do { \
    _Pragma("unroll") for (int jj = 0; jj < 2; ++jj) { \
      dst[jj][0] = *(const bf16x8*)(smem + 65536 + (buf) * 32768 + bRd + (qj) * 4096 + jj * 2048 + swz0); \
      dst[jj][1] = *(const bf16x8*)(smem + 65536 + (buf) * 32768 + bRd + (qj) * 4096 + jj * 2048 + swz1); } \
  } while (0)
#define MF_Q(af_, bf_, qi, jh) do { \
    __builtin_amdgcn_s_setprio(1); \
    _Pragma("unroll") for (int ii = 0; ii < 4; ++ii) \
      _Pragma("unroll") for (int jj = 0; jj < 2; ++jj) { \
        acc[(qi)*4+ii][(jh)*2+jj] = __builtin_amdgcn_mfma_f32_16x16x32_bf16(af_[ii][0], bf_[jj][0], acc[(qi)*4+ii][(jh)*2+jj], 0, 0, 0); \
        acc[(qi)*4+ii][(jh)*2+jj] = __builtin_amdgcn_mfma_f32_16x16x32_bf16(af_[ii][1], bf_[jj][1], acc[(qi)*4+ii][(jh)*2+jj], 0, 0, 0); } \
    __builtin_amdgcn_s_setprio(0); \
  } while (0)

  // prologue: tile0 all units (buf0), tile1 A.ha,B.ha,B.hb (buf1); A.hb(t1) staged in-loop p0
  STG_A(0, 0, 0);
  STG_B(0, 0, 0);
  STG_B(1, 0, 0);
  STG_A(1, 0, 0);
  STG_A(0, 1, 64);
  STG_B(0, 1, 64);
  STG_B(1, 1, 64);
  VMCNT(8);   // tile0 A.ha/B.ha/B.hb landed by all waves before barrier
  BAR();

#pragma unroll 1
  for (int j = 0; j < 8; ++j) {
    const int kt1 = j * 128 + 64;                // tile 2j+1
    const int kc2 = (j * 128 + 128) & 1023;      // tile 2j+2 (wraps harmlessly at tail)
    const int kc3 = (j * 128 + 192) & 1023;      // tile 2j+3
    bf16x8 afA[4][2], afB[4][2], bf0[2][2], bf1[2][2];
    // p0: reads A.ha,B.ha (buf0); stages A.hb(t2j+1 -> buf1)
    VMCNT(8); LD_A(afA, 0, 0); LD_B(bf0, 0, 0); STG_A(1, 1, kt1);
    BAR(); MF_Q(afA, bf0, 0, 0); BAR();
    // p1: reads B.hb (buf0); stages A.ha(t2j+2 -> buf0)
    VMCNT(8); LD_B(bf1, 0, 1); STG_A(0, 0, kc2);
    BAR(); MF_Q(afA, bf1, 0, 1); BAR();
    // p2: reads A.hb (buf0); stages B.ha(t2j+2)
    VMCNT(8); LD_A(afB, 0, 1); STG_B(0, 0, kc2);
    BAR(); MF_Q(afB, bf1, 1, 1); BAR();
    // p3: regs only; stages B.hb(t2j+2)
    VMCNT(8); STG_B(1, 0, kc2);
    BAR(); MF_Q(afB, bf0, 1, 0); BAR();
    // p4: reads A.ha,B.ha (buf1); stages A.hb(t2j+2)
    VMCNT(8); LD_A(afA, 1, 0); LD_B(bf0, 1, 0); STG_A(1, 0, kc2);
    BAR(); MF_Q(afA, bf0, 0, 0); BAR();
    // p5: reads B.hb (buf1); stages A.ha(t2j+3 -> buf1)
    VMCNT(8); LD_B(bf1, 1, 1); STG_A(0, 1, kc3);
    BAR(); MF_Q(afA, bf1, 0, 1); BAR();
    // p6: reads A.hb (buf1); stages B.ha(t2j+3)
    VMCNT(8); LD_A(afB, 1, 1); STG_B(0, 1, kc3);
    BAR(); MF_Q(afB, bf1, 1, 1); BAR();
    // p7: regs only; stages B.hb(t2j+3)
    VMCNT(8); STG_B(1, 1, kc3);
    BAR(); MF_Q(afB, bf0, 1, 0); BAR();
  }

  VMCNT(0);   // drain tail garbage stages before LDS reuse
  BAR();

  // ---------------- epilogue: bias + relu + routing weight + e-reduce ----------------
  float* outb = (float*)smem;                 // [256][33] padded
  const int bidx = m0 >> 11;
  const float rw = routing[bidx * Edim + (lane & 7)];
  const int dblk = (lane >> 3) & 1;
  const bool writer = ((lane & 7) == 0);
#pragma unroll
  for (int j = 0; j < 4; ++j) {
    const int col0 = wcn * 64 + j * 16;
    const float bias = be[(lane & 7) * Hdim + (n0 >> 3) + (col0 >> 3) + dblk];
#pragma unroll
    for (int i = 0; i < 8; ++i) {
#pragma unroll
      for (int r = 0; r < 4; ++r) {
        float v = fmaxf(acc[i][j][r] + bias, 0.f) * rw;
        v += __shfl_xor(v, 1, 64);
        v += __shfl_xor(v, 2, 64);
        v += __shfl_xor(v, 4, 64);
        if (writer) {
          const int row = wr * 128 + i * 16 + ((lane >> 4) << 2) + r;
          outb[row * 33 + (col0 >> 3) + dblk] = v;
        }
      }
    }
  }
  BAR();
  const size_t obase = (size_t)m0 * Hdim + (n0 >> 3);
#pragma unroll
  for (int it = 0; it < 4; ++it) {
    const int r = it * 64 + (t >> 3);
    const int c = (t & 7) * 4;
    float4 vv;
    vv.x = outb[r * 33 + c];
    vv.y = outb[r * 33 + c + 1];
    vv.z = outb[r * 33 + c + 2];
    vv.w = outb[r * 33 + c + 3];
    *(float4*)(out + obase + (size_t)r * Hdim + c) = vv;
  }
#undef STG_A
#undef STG_B
#undef LD_A
#undef LD_B
#undef MF_Q
}

extern "C" void kernel_launch(void* const* d_in, const int* in_sizes, int n_in,
                              void* d_out, int out_size, void* d_ws, size_t ws_size,
                              hipStream_t stream) {
  const float* x   = (const float*)d_in[0];
  const float* We  = (const float*)d_in[1];
  const float* be  = (const float*)d_in[2];
  const float* Wr1 = (const float*)d_in[3];
  const float* br1 = (const float*)d_in[4];
  const float* Wr2 = (const float*)d_in[5];
  const float* br2 = (const float*)d_in[6];
  float* out = (float*)d_out;

  char* ws = (char*)d_ws;
  unsigned short* xb = (unsigned short*)ws;                  // 33,554,432 B
  unsigned short* wt = (unsigned short*)(ws + 33554432);     // 16,777,216 B
  float* part    = (float*)(ws + 50331648);                  //  4,194,304 B
  float* hbuf    = (float*)(ws + 54525952);                  //     32,768 B
  float* routing = (float*)(ws + 54558720);                  //        256 B

  hipFuncSetAttribute((const void*)k_moe_gemm,
                      hipFuncAttributeMaxDynamicSharedMemorySize, 131072);

  k_convert_mean<<<dim3(Sdim / 32, Bdim), 256, 0, stream>>>(x, xb, part);
  k_transpose_w<<<dim3(Hdim / 64, Hdim / 64, Edim), 256, 0, stream>>>(We, wt);
  k_router1<<<dim3(Hdim / 256, Bdim), 256, 0, stream>>>(part, Wr1, br1, hbuf);
  k_router2<<<1, 64, 0, stream>>>(hbuf, Wr2, br2, routing);
  k_moe_gemm<<<dim3(2048), 512, 131072, stream>>>(xb, wt, be, routing, out);
}